// Round 15
// baseline (115.223 us; speedup 1.0000x reference)
//
#include <hip/hip_runtime.h>
#include <stdint.h>

#define NROWS 8192
#define DIM   2048
#define MARGIN 2.0f
#define SCALEQ (127.0f / 6.0f)          // quantize scale
#define S2     ((6.0f / 127.0f) * (6.0f / 127.0f))   // dequant^2

// ---- 128x256 i8 tile kernel geometry (byte units) ----
#define BKB     128                      // K-bytes (=elems) per tile-step
#define NKT     (DIM / BKB)              // 16 K-tiles
#define NDIAG   32                       // odd-row diagonal 128² tiles
#define NFULL   1024                     // 128x256 full blocks (= 8*128)
// SINGLE-buffered LDS: A [0,16K) 128x128B, B [16K,48K) 256x128B
#define BOFF    16384

typedef __attribute__((ext_vector_type(4)))  int  int4v;    // 16B operand
typedef __attribute__((ext_vector_type(16))) int  int16v;   // 32x32 i32 acc
typedef unsigned char uchar;

__device__ __forceinline__ uint pack4(float4 v) {
    int q0 = (int)__builtin_rintf(v.x * SCALEQ);
    int q1 = (int)__builtin_rintf(v.y * SCALEQ);
    int q2 = (int)__builtin_rintf(v.z * SCALEQ);
    int q3 = (int)__builtin_rintf(v.w * SCALEQ);
    q0 = min(max(q0, -127), 127); q1 = min(max(q1, -127), 127);
    q2 = min(max(q2, -127), 127); q3 = min(max(q3, -127), 127);
    return (uint)(q0 & 0xFF) | ((uint)(q1 & 0xFF) << 8) |
           ((uint)(q2 & 0xFF) << 16) | ((uint)(q3 & 0xFF) << 24);
}

// ---------------- kernel 1: fp32 -> i8 quantize + fp32 row sum of squares ---
// sq from the fp32 ORIGINALS: cancels the quantization distance-inflation bias.
__global__ __launch_bounds__(256) void prep_kernel(const float* __restrict__ p,
                                                   uchar* __restrict__ pb,
                                                   float* __restrict__ sq) {
    int row = blockIdx.x;
    int t = threadIdx.x;
    const float4* prow = (const float4*)(p + (size_t)row * DIM);
    uint* qrow = (uint*)(pb + (size_t)row * DIM);
    float4 a = prow[t];
    float4 b = prow[t + 256];
    float s = a.x * a.x + a.y * a.y + a.z * a.z + a.w * a.w
            + b.x * b.x + b.y * b.y + b.z * b.z + b.w * b.w;
    qrow[t] = pack4(a);
    qrow[t + 256] = pack4(b);
#pragma unroll
    for (int o = 32; o > 0; o >>= 1) s += __shfl_down(s, o, 64);
    __shared__ float wsums[4];
    int lane = t & 63, wvv = t >> 6;
    if (lane == 0) wsums[wvv] = s;
    __syncthreads();
    if (t == 0) sq[row] = wsums[0] + wsums[1] + wsums[2] + wsums[3];
}

// ---------------- staging: global -> LDS, linear dest, pre-swizzled src -----
// 256 threads; NCH chunks of 32 rows x 128B (4KB each); region offset ROFF.
// t >= NKT clamps to NKT-1 (dead data; single buffer, window-safe).
template<int NCH, int ROFF>
__device__ __forceinline__ void stage_r(const uchar* __restrict__ pb,
                                        uchar* lds, int t, int rbase, int tid) {
    if (t >= NKT) t = NKT - 1;
    const uchar* g0 = pb + (size_t)rbase * DIM + t * BKB;
    uchar* l0 = lds + ROFF;
#pragma unroll
    for (int r = 0; r < NCH; ++r) {
        int row = r * 32 + (tid >> 3);
        int c8 = (tid & 7) ^ ((tid >> 3) & 7);         // pre-swizzled 16B slot
        const uchar* g = g0 + (size_t)row * DIM + c8 * 16;
        uchar* l = l0 + r * 4096 + (tid >> 6) * 1024;  // wave-uniform (+lane*16 HW)
        __builtin_amdgcn_global_load_lds(
            (const __attribute__((address_space(1))) uint32_t*)g,
            (__attribute__((address_space(3))) uint32_t*)l, 16, 0, 0);
    }
}

#define BARF()   do { __builtin_amdgcn_s_barrier(); \
                      asm volatile("" ::: "memory"); } while (0)
#define WAITL()  asm volatile("s_waitcnt lgkmcnt(0)" ::: "memory")
#define WAITV0() asm volatile("s_waitcnt vmcnt(0)" ::: "memory")
#define PRIO1()  __builtin_amdgcn_s_setprio(1)
#define PRIO0()  __builtin_amdgcn_s_setprio(0)
#define SB0()    __builtin_amdgcn_sched_barrier(0)

// swizzled ds_read of 16B i8 frags: row stride 128B, slot ^= (row&7) = (lane&7)
// FULL path: per-wave 128x64; all waves read all of A; B strip by wave.
#define RD_AF(MT)                                                              \
    _Pragma("unroll") for (int s = 0; s < 4; ++s)                              \
        af[MT][s] = *(const int4v*)&lds[                                       \
            (((MT) * 32 + (lane & 31)) * 128) +                                \
            (((2 * s + kh) ^ (lane & 7)) * 16)];

#define RD_BF(NT)                                                              \
    _Pragma("unroll") for (int s = 0; s < 4; ++s)                              \
        bf[NT][s] = *(const int4v*)&lds[BOFF +                                 \
            ((wv * 64 + (NT) * 32 + (lane & 31)) * 128) +                      \
            (((2 * s + kh) ^ (lane & 7)) * 16)];

#define MFMA_MT(MT)                                                            \
    _Pragma("unroll") for (int s = 0; s < 4; ++s)                              \
    _Pragma("unroll") for (int nt = 0; nt < 2; ++nt)                           \
        acc[MT][nt] = __builtin_amdgcn_mfma_i32_32x32x32_i8(                   \
            af[MT][s], bf[nt][s], acc[MT][nt], 0, 0, 0);

// DIAG path: per-wave 64x64 (2x2 wave grid), R14-proven geometry.
#define RD_DA(MT)                                                              \
    _Pragma("unroll") for (int s = 0; s < 4; ++s)                              \
        af[MT][s] = *(const int4v*)&lds[                                       \
            ((wr * 64 + (MT) * 32 + (lane & 31)) * 128) +                      \
            (((2 * s + kh) ^ (lane & 7)) * 16)];

#define RD_DB(NT)                                                              \
    _Pragma("unroll") for (int s = 0; s < 4; ++s)                              \
        bf[NT][s] = *(const int4v*)&lds[BOFF +                                 \
            ((wc * 64 + (NT) * 32 + (lane & 31)) * 128) +                      \
            (((2 * s + kh) ^ (lane & 7)) * 16)];

#define MFMA_D(MT)                                                             \
    _Pragma("unroll") for (int s = 0; s < 4; ++s)                              \
    _Pragma("unroll") for (int nt = 0; nt < 2; ++nt)                           \
        acc[MT][nt] = __builtin_amdgcn_mfma_i32_32x32x32_i8(                   \
            af[MT][s], bf[nt][s], acc[MT][nt], 0, 0, 0);

// ---------------- kernel 2: triangular Gram + fused loss --------------------
// Grid = 32 diag blocks (odd-row 128² tiles, dispatched first) + 1024 full
// 128x256 blocks. 256 threads, 4 waves (1 wave/SIMD), 48KB LDS, launch_bounds
// (256,2) caps regs at 256/wave combined -> 2 blocks/CU co-resident (m114
// overlap: one block's MFMA phase hides the other's LDS bursts + drains).
__global__ __launch_bounds__(256, 2) void tile2_kernel(
    const uchar* __restrict__ pb, const float* __restrict__ sq,
    const int* __restrict__ gt, double* __restrict__ accum) {

    __shared__ uchar lds[49152];   // A 16KB | B 32KB, single buffer
    __shared__ float wsum[4];

    const int bx = (int)blockIdx.x;
    const int tid = threadIdx.x;
    const int lane = tid & 63;
    const int kh = lane >> 5;            // K-half within a 32-wide slice
    const int wv = tid >> 6;             // wave 0..3

    const float invd = 1.0f / (float)DIM;
    float lsum = 0.f;

    if (bx >= NDIAG) {
        // ---- FULL path: 128 rows (tile ti) x 256 cols (pair J) ----
        int f = bx - NDIAG;
        f = (f & 7) * 128 + (f >> 3);          // bijective XCD swizzle (1024=8*128)
        int J = (int)sqrtf((float)f + 0.5f);   // cum(J) = J^2
        while ((J + 1) * (J + 1) <= f) ++J;
        while (J * J > f) --J;
        const int ti = f - J * J;              // 0..2J  (row 128-tile)
        const int ibase = ti * 128;
        const int jbase = J * 256;

        int16v acc[4][2] = {};                 // 128 AGPR
        int4v af[4][4];                        // 64 VGPR
        int4v bf[2][4];                        // 32 VGPR

        stage_r<4, 0>(pb, lds, 0, ibase, tid);
        stage_r<8, BOFF>(pb, lds, 0, jbase, tid);
        WAITV0();
        BARF();

#pragma unroll 1
        for (int t = 0; t < NKT; ++t) {
            // 24 ds_reads issued up-front; compiler gates MFMA clusters with
            // counted lgkmcnt, so reads flow under the first MFMA cluster.
            RD_AF(0); RD_AF(1);
            RD_BF(0); RD_BF(1);
            RD_AF(2); RD_AF(3);
            PRIO1(); MFMA_MT(0); MFMA_MT(1); PRIO0();
            WAITL(); BARF();
            // stages(t+1) overwrite the single buffer (all reads closed);
            // second MFMA cluster (reg-only) covers the stage drain.
            stage_r<4, 0>(pb, lds, t + 1, ibase, tid);
            stage_r<8, BOFF>(pb, lds, t + 1, jbase, tid);
            SB0();
            PRIO1(); MFMA_MT(2); MFMA_MT(3); PRIO0();
            WAITV0();
            BARF();
        }

        // fused epilogue: dequant -> d2 -> contrastive term -> weighted sum
        int j0 = jbase + wv * 64 + (lane & 31);
        float sqj[2]; int gj[2];
#pragma unroll
        for (int nt = 0; nt < 2; ++nt) { int j = j0 + nt * 32; sqj[nt] = sq[j]; gj[nt] = gt[j]; }
#pragma unroll
        for (int mt = 0; mt < 4; ++mt) {
#pragma unroll
            for (int q = 0; q < 4; ++q) {
#pragma unroll
                for (int rr = 0; rr < 4; ++rr) {
                    int i = ibase + mt * 32 + rr + 8 * q + 4 * kh;
                    float sqi = sq[i];
                    int gi = gt[i];
#pragma unroll
                    for (int nt = 0; nt < 2; ++nt) {
                        int j = j0 + nt * 32;
                        float dot = S2 * (float)acc[mt][nt][q * 4 + rr];
                        float d2 = fmaxf(sqi + sqj[nt] - 2.0f * dot, 0.0f) * invd;
                        float term = (gi == gj[nt]) ? d2 : fmaxf(MARGIN - d2, 0.0f);
                        // j-tile above diagonal: w=2 (mirror). j-tile == ti:
                        // full 128² block present -> w=1 off-diag, 2 on i==j.
                        float w = ((j >> 7) != ti) ? 2.0f : ((i == j) ? 2.0f : 1.0f);
                        lsum += w * term;
                    }
                }
            }
        }
    } else {
        // ---- DIAG path: odd-row diagonal 128² tile, 2x2 wave grid ----
        const int td = 2 * bx + 1;
        const int ibase = td * 128;
        const int wr = wv >> 1;
        const int wc = wv & 1;

        int16v acc[2][2] = {};
        int4v af[2][4], bf[2][4];

        stage_r<4, 0>(pb, lds, 0, ibase, tid);
        stage_r<4, BOFF>(pb, lds, 0, ibase, tid);
        WAITV0();
        BARF();

#pragma unroll 1
        for (int t = 0; t < NKT; ++t) {
            RD_DA(0); RD_DB(0); RD_DB(1); RD_DA(1);
            PRIO1(); MFMA_D(0); PRIO0();
            WAITL(); BARF();
            stage_r<4, 0>(pb, lds, t + 1, ibase, tid);
            stage_r<4, BOFF>(pb, lds, t + 1, ibase, tid);
            SB0();
            PRIO1(); MFMA_D(1); PRIO0();
            WAITV0();
            BARF();
        }

        int j0 = ibase + wc * 64 + (lane & 31);
        float sqj[2]; int gj[2];
#pragma unroll
        for (int nt = 0; nt < 2; ++nt) { int j = j0 + nt * 32; sqj[nt] = sq[j]; gj[nt] = gt[j]; }
#pragma unroll
        for (int mt = 0; mt < 2; ++mt) {
#pragma unroll
            for (int q = 0; q < 4; ++q) {
#pragma unroll
                for (int rr = 0; rr < 4; ++rr) {
                    int i = ibase + wr * 64 + mt * 32 + rr + 8 * q + 4 * kh;
                    float sqi = sq[i];
                    int gi = gt[i];
#pragma unroll
                    for (int nt = 0; nt < 2; ++nt) {
                        int j = j0 + nt * 32;
                        float dot = S2 * (float)acc[mt][nt][q * 4 + rr];
                        float d2 = fmaxf(sqi + sqj[nt] - 2.0f * dot, 0.0f) * invd;
                        float term = (gi == gj[nt]) ? d2 : fmaxf(MARGIN - d2, 0.0f);
                        float w = (i == j) ? 2.0f : 1.0f;   // full block both orders
                        lsum += w * term;
                    }
                }
            }
        }
    }

#pragma unroll
    for (int o = 32; o > 0; o >>= 1) lsum += __shfl_down(lsum, o, 64);
    if (lane == 0) wsum[wv] = lsum;
    __syncthreads();
    if (tid == 0)
        atomicAdd(accum, (double)(wsum[0] + wsum[1] + wsum[2] + wsum[3]));
}

// ---------------- kernel 3: finalize ----------------------------------------
__global__ void finalize_kernel(const double* __restrict__ accum,
                                float* __restrict__ out) {
    if (threadIdx.x == 0)
        out[0] = (float)(accum[0] * (1.0 / ((double)NROWS * (double)(NROWS - 1))));
}

extern "C" void kernel_launch(void* const* d_in, const int* in_sizes, int n_in,
                              void* d_out, int out_size, void* d_ws, size_t ws_size,
                              hipStream_t stream) {
    (void)in_sizes; (void)n_in; (void)out_size; (void)ws_size;
    const float* p = (const float*)d_in[0];
    const int* gt = (const int*)d_in[1];
    float* out = (float*)d_out;

    // ws layout: pb 16MB i8 | sq 32KB | accum 8B
    uchar* pb = (uchar*)d_ws;
    size_t off = (size_t)NROWS * DIM;                   // 16,777,216
    float* sq = (float*)((char*)d_ws + off);
    off += (size_t)NROWS * sizeof(float);               // +32 KB
    double* accum = (double*)((char*)d_ws + off);

    (void)hipMemsetAsync(accum, 0, sizeof(double), stream);
    prep_kernel<<<NROWS, 256, 0, stream>>>(p, pb, sq);
    tile2_kernel<<<NDIAG + NFULL, 256, 0, stream>>>(pb, sq, gt, accum);
    finalize_kernel<<<1, 64, 0, stream>>>(accum, out);
}